// Round 1
// baseline (632.506 us; speedup 1.0000x reference)
//
#include <hip/hip_runtime.h>
#include <cstdint>
#include <cstddef>

constexpr int B = 8, S = 4096, D = 512, R = 16;
constexpr int M = B * S;                         // 32768 rows
constexpr long long OUT_ELEMS = (long long)M * 3 * D;  // 50331648

// ---------------- Kernel A: occ logits (fp64 accum) -> argmax + top prob ----
// One wave per row; lane-strided fp64 dot for 16 logits, butterfly reduce.
__global__ __launch_bounds__(256) void occ_kernel(
    const float* __restrict__ x, const float* __restrict__ occ_w,
    const float* __restrict__ occ_b, int* __restrict__ reg_indx,
    float* __restrict__ reg_logit)
{
    const int wave = threadIdx.x >> 6, lane = threadIdx.x & 63;
    const int row = blockIdx.x * 4 + wave;
    const float* xr = x + (size_t)row * D;
    double acc[R];
#pragma unroll
    for (int r = 0; r < R; ++r) acc[r] = 0.0;
#pragma unroll
    for (int it = 0; it < D / 64; ++it) {
        const int d = it * 64 + lane;
        const double xv = (double)xr[d];
        const float* wr = occ_w + d * R;     // 16 contiguous floats
#pragma unroll
        for (int r = 0; r < R; ++r) acc[r] += xv * (double)wr[r];
    }
#pragma unroll
    for (int r = 0; r < R; ++r) {
        double v = acc[r];
#pragma unroll
        for (int off = 32; off > 0; off >>= 1) v += __shfl_xor(v, off, 64);
        acc[r] = v + (double)occ_b[r];
    }
    // first-occurrence argmax (matches np.argmax)
    double mx = acc[0]; int idx = 0;
#pragma unroll
    for (int r = 1; r < R; ++r) if (acc[r] > mx) { mx = acc[r]; idx = r; }
    double sum = 0.0;
#pragma unroll
    for (int r = 0; r < R; ++r) sum += exp(acc[r] - mx);
    if (lane == 0) { reg_indx[row] = idx; reg_logit[row] = (float)(1.0 / sum); }
}

// ---------------- Kernel B: per-batch counts + loss partial (deterministic) --
__global__ __launch_bounds__(256) void loss_kernel(
    const int* __restrict__ reg_indx, const float* __restrict__ reg_logit,
    int* __restrict__ counts, double* __restrict__ loss_b)
{
    const int b = blockIdx.x, t = threadIdx.x;
    __shared__ double ssum[R][257];
    __shared__ int    scnt[R][257];
#pragma unroll
    for (int r = 0; r < R; ++r) { ssum[r][t] = 0.0; scnt[r][t] = 0; }
    __syncthreads();
    for (int s = t; s < S; s += 256) {
        const int r = reg_indx[b * S + s];
        ssum[r][t] += (double)reg_logit[b * S + s];
        scnt[r][t] += 1;
    }
    __syncthreads();
    for (int off = 128; off > 0; off >>= 1) {
        if (t < off) {
#pragma unroll
            for (int r = 0; r < R; ++r) {
                ssum[r][t] += ssum[r][t + off];
                scnt[r][t] += scnt[r][t + off];
            }
        }
        __syncthreads();
    }
    if (t == 0) {
        double lb = 0.0;
#pragma unroll
        for (int r = 0; r < R; ++r) {
            counts[b * R + r] = scnt[r][0];
            const double mean = ssum[r][0] / (double)S;
            lb += mean * mean;
        }
        loss_b[b] = lb;
    }
}

// ---------------- c2 = relu(relu(b1) @ w2 + b2): the "all-masked row" vector -
__global__ __launch_bounds__(256) void c2_kernel(
    const float* __restrict__ b1, const float* __restrict__ w2,
    const float* __restrict__ b2, float* __restrict__ c2)
{
    __shared__ float c1[D];
    const int t = threadIdx.x;
    c1[t]       = fmaxf(b1[t], 0.f);
    c1[t + 256] = fmaxf(b1[t + 256], 0.f);
    __syncthreads();
    for (int d = t; d < D; d += 256) {
        float acc = b2[d];
        for (int k = 0; k < D; ++k) acc += c1[k] * w2[(size_t)k * D + d];
        c2[d] = fmaxf(acc, 0.f);
    }
}

// ---------------- init regvec[b][r][:] = (count<S) ? c2 : 0 ------------------
__global__ __launch_bounds__(256) void init_regvec_kernel(
    const int* __restrict__ counts, const float* __restrict__ c2,
    float* __restrict__ regvec)
{
    const int idx = blockIdx.x * 256 + threadIdx.x;   // B*R*D total
    const int d = idx & (D - 1);
    const int br = idx >> 9;
    regvec[idx] = (counts[br] < S) ? c2[d] : 0.f;
}

// ---------------- fp32 tiled GEMM, 64x64x32, 256 thr, 4x4 micro-tile --------
constexpr int BM = 64, BN = 64, BK = 32;

__global__ __launch_bounds__(256) void gemm1_kernel(
    const float* __restrict__ A, const float* __restrict__ Wt,
    const float* __restrict__ bias, float* __restrict__ H)
{
    __shared__ float As[BK][BM + 4];   // +4 keeps float4 rows 16B-aligned
    __shared__ float Bs[BK][BN];
    const int tid = threadIdx.x;
    const int tx = tid & 15, ty = tid >> 4;
    const int row0 = blockIdx.y * BM, col0 = blockIdx.x * BN;
    const int aRow = tid >> 2, aK = (tid & 3) * 8;
    const int bRow = tid >> 3, bN = (tid & 7) * 8;
    float acc[4][4] = {};
    for (int kt = 0; kt < D; kt += BK) {
        const float4 a0 = *(const float4*)&A[(size_t)(row0 + aRow) * D + kt + aK];
        const float4 a1 = *(const float4*)&A[(size_t)(row0 + aRow) * D + kt + aK + 4];
        const float4 w0 = *(const float4*)&Wt[(size_t)(kt + bRow) * D + col0 + bN];
        const float4 w1v = *(const float4*)&Wt[(size_t)(kt + bRow) * D + col0 + bN + 4];
        __syncthreads();
        As[aK + 0][aRow] = a0.x; As[aK + 1][aRow] = a0.y;
        As[aK + 2][aRow] = a0.z; As[aK + 3][aRow] = a0.w;
        As[aK + 4][aRow] = a1.x; As[aK + 5][aRow] = a1.y;
        As[aK + 6][aRow] = a1.z; As[aK + 7][aRow] = a1.w;
        *(float4*)&Bs[bRow][bN]     = w0;
        *(float4*)&Bs[bRow][bN + 4] = w1v;
        __syncthreads();
#pragma unroll
        for (int k = 0; k < BK; ++k) {
            const float4 av = *(const float4*)&As[k][ty * 4];
            const float4 bv = *(const float4*)&Bs[k][tx * 4];
            const float a[4] = {av.x, av.y, av.z, av.w};
            const float b[4] = {bv.x, bv.y, bv.z, bv.w};
#pragma unroll
            for (int i = 0; i < 4; ++i)
#pragma unroll
                for (int j = 0; j < 4; ++j) acc[i][j] += a[i] * b[j];
        }
    }
    const float4 bv = *(const float4*)&bias[col0 + tx * 4];
    const float bb[4] = {bv.x, bv.y, bv.z, bv.w};
#pragma unroll
    for (int i = 0; i < 4; ++i) {
        const int row = row0 + ty * 4 + i;
        float4 o;
        o.x = fmaxf(acc[i][0] + bb[0], 0.f);
        o.y = fmaxf(acc[i][1] + bb[1], 0.f);
        o.z = fmaxf(acc[i][2] + bb[2], 0.f);
        o.w = fmaxf(acc[i][3] + bb[3], 0.f);
        *(float4*)&H[(size_t)row * D + col0 + tx * 4] = o;
    }
}

// GEMM2 + segmented max into regvec[b][reg][col] (relu >= 0 -> uint atomicMax)
__global__ __launch_bounds__(256) void gemm2max_kernel(
    const float* __restrict__ A, const float* __restrict__ Wt,
    const float* __restrict__ bias, const int* __restrict__ reg_indx,
    float* __restrict__ regvec)
{
    __shared__ float As[BK][BM + 4];
    __shared__ float Bs[BK][BN];
    __shared__ unsigned redmax[R][BN];
    __shared__ int rowreg[BM];
    const int tid = threadIdx.x;
    const int tx = tid & 15, ty = tid >> 4;
    const int row0 = blockIdx.y * BM, col0 = blockIdx.x * BN;
    if (tid < BM) rowreg[tid] = reg_indx[row0 + tid];
    const int aRow = tid >> 2, aK = (tid & 3) * 8;
    const int bRow = tid >> 3, bN = (tid & 7) * 8;
    float acc[4][4] = {};
    for (int kt = 0; kt < D; kt += BK) {
        const float4 a0 = *(const float4*)&A[(size_t)(row0 + aRow) * D + kt + aK];
        const float4 a1 = *(const float4*)&A[(size_t)(row0 + aRow) * D + kt + aK + 4];
        const float4 w0 = *(const float4*)&Wt[(size_t)(kt + bRow) * D + col0 + bN];
        const float4 w1v = *(const float4*)&Wt[(size_t)(kt + bRow) * D + col0 + bN + 4];
        __syncthreads();
        As[aK + 0][aRow] = a0.x; As[aK + 1][aRow] = a0.y;
        As[aK + 2][aRow] = a0.z; As[aK + 3][aRow] = a0.w;
        As[aK + 4][aRow] = a1.x; As[aK + 5][aRow] = a1.y;
        As[aK + 6][aRow] = a1.z; As[aK + 7][aRow] = a1.w;
        *(float4*)&Bs[bRow][bN]     = w0;
        *(float4*)&Bs[bRow][bN + 4] = w1v;
        __syncthreads();
#pragma unroll
        for (int k = 0; k < BK; ++k) {
            const float4 av = *(const float4*)&As[k][ty * 4];
            const float4 bv = *(const float4*)&Bs[k][tx * 4];
            const float a[4] = {av.x, av.y, av.z, av.w};
            const float b[4] = {bv.x, bv.y, bv.z, bv.w};
#pragma unroll
            for (int i = 0; i < 4; ++i)
#pragma unroll
                for (int j = 0; j < 4; ++j) acc[i][j] += a[i] * b[j];
        }
    }
    // epilogue: bias+relu, LDS segmented max, then global atomics
    unsigned* rm = &redmax[0][0];
#pragma unroll
    for (int q = 0; q < 4; ++q) rm[tid + q * 256] = 0u;
    __syncthreads();
    const float4 bv = *(const float4*)&bias[col0 + tx * 4];
    const float bb[4] = {bv.x, bv.y, bv.z, bv.w};
#pragma unroll
    for (int i = 0; i < 4; ++i) {
        const int rr = rowreg[ty * 4 + i];
#pragma unroll
        for (int j = 0; j < 4; ++j) {
            const float v = fmaxf(acc[i][j] + bb[j], 0.f);
            atomicMax(&redmax[rr][tx * 4 + j], __float_as_uint(v));
        }
    }
    __syncthreads();
    const int b = row0 >> 12;   // 4096 rows per batch, BM divides 4096
#pragma unroll
    for (int q = 0; q < 4; ++q) {
        const int idx = tid + q * 256;
        const int r = idx >> 6, c = idx & 63;
        atomicMax((unsigned*)&regvec[(((size_t)b * R + r) << 9) + col0 + c], rm[idx]);
    }
}

// ---------------- output assembly: [x | regvec[reg_indx] | g] ----------------
__global__ __launch_bounds__(128) void out_kernel(
    const float* __restrict__ x, const float* __restrict__ g,
    const float* __restrict__ regvec, const int* __restrict__ reg_indx,
    float* __restrict__ out)
{
    const int row = blockIdx.x;        // 0..M-1
    const int t = threadIdx.x;         // 128 threads, float4 each = 512 floats
    const int b = row >> 12;
    const int r = reg_indx[row];
    const float4* xr = (const float4*)(x + (size_t)row * D);
    const float4* rv = (const float4*)(regvec + ((size_t)b * R + r) * D);
    const float4* gr = (const float4*)(g + (size_t)b * D);
    float4* o = (float4*)(out + (size_t)row * 3 * D);
    o[t]       = xr[t];
    o[128 + t] = rv[t];
    o[256 + t] = gr[t];
}

__global__ void loss_final_kernel(const double* __restrict__ loss_b,
                                  float* __restrict__ out_loss)
{
    if (threadIdx.x == 0) {
        double s = 0.0;
        for (int b = 0; b < B; ++b) s += loss_b[b];
        *out_loss = (float)(s / (double)B);
    }
}

extern "C" void kernel_launch(void* const* d_in, const int* in_sizes, int n_in,
                              void* d_out, int out_size, void* d_ws, size_t ws_size,
                              hipStream_t stream)
{
    (void)in_sizes; (void)n_in; (void)out_size;
    const float* x     = (const float*)d_in[0];
    const float* g_vec = (const float*)d_in[1];
    const float* occ_w = (const float*)d_in[2];
    const float* occ_b = (const float*)d_in[3];
    const float* w1    = (const float*)d_in[4];
    const float* b1    = (const float*)d_in[5];
    const float* w2    = (const float*)d_in[6];
    const float* b2    = (const float*)d_in[7];
    float* out = (float*)d_out;

    char* ws = (char*)d_ws;
    size_t off = 0;
    double* loss_b   = (double*)(ws + off); off += 64;
    int*    reg_indx = (int*)(ws + off);    off += (size_t)M * 4;
    float*  reg_logit= (float*)(ws + off);  off += (size_t)M * 4;
    int*    counts   = (int*)(ws + off);    off += B * R * 4;
    float*  c2       = (float*)(ws + off);  off += D * 4;
    off = (off + 255) & ~(size_t)255;
    float*  regvec   = (float*)(ws + off);  off += (size_t)B * R * D * 4;
    off = (off + 255) & ~(size_t)255;
    // h1 scratch (64 MB): use ws if it fits, else stash in d_out (fully
    // overwritten later by out_kernel, which runs after gemm2 consumed h1).
    float* h1 = (ws_size >= off + (size_t)M * D * 4)
                    ? (float*)(ws + off) : (float*)d_out;

    hipLaunchKernelGGL(occ_kernel, dim3(M / 4), dim3(256), 0, stream,
                       x, occ_w, occ_b, reg_indx, reg_logit);
    hipLaunchKernelGGL(loss_kernel, dim3(B), dim3(256), 0, stream,
                       reg_indx, reg_logit, counts, loss_b);
    hipLaunchKernelGGL(c2_kernel, dim3(1), dim3(256), 0, stream,
                       b1, w2, b2, c2);
    hipLaunchKernelGGL(init_regvec_kernel, dim3(B * R * D / 256), dim3(256), 0, stream,
                       counts, c2, regvec);
    hipLaunchKernelGGL(gemm1_kernel, dim3(D / BN, M / BM), dim3(256), 0, stream,
                       x, w1, b1, h1);
    hipLaunchKernelGGL(gemm2max_kernel, dim3(D / BN, M / BM), dim3(256), 0, stream,
                       h1, w2, b2, reg_indx, regvec);
    hipLaunchKernelGGL(out_kernel, dim3(M), dim3(128), 0, stream,
                       x, g_vec, regvec, reg_indx, out);
    hipLaunchKernelGGL(loss_final_kernel, dim3(1), dim3(64), 0, stream,
                       loss_b, out + OUT_ELEMS);
}

// Round 2
// 239.520 us; speedup vs baseline: 2.6407x; 2.6407x over previous
//
#include <hip/hip_runtime.h>
#include <cstdint>
#include <cstddef>

constexpr int B = 8, S = 4096, D = 512, R = 16;
constexpr int M = B * S;                         // 32768 rows
constexpr long long OUT_ELEMS = (long long)M * 3 * D;  // 50331648

typedef short short8 __attribute__((ext_vector_type(8)));
typedef float f32x4 __attribute__((ext_vector_type(4)));

__device__ __forceinline__ ushort f2bf(float f) {
    union { float f; unsigned u; } v; v.f = f;
    return (ushort)((v.u + 0x7fffu + ((v.u >> 16) & 1u)) >> 16);
}

__device__ __forceinline__ void gload_lds16(const void* g, void* l) {
    __builtin_amdgcn_global_load_lds(
        (const __attribute__((address_space(1))) void*)g,
        (__attribute__((address_space(3))) void*)l, 16, 0, 0);
}

// ---------------- occ logits (fp64) -> argmax + top prob; also emits x->bf16
__global__ __launch_bounds__(256) void occ_kernel(
    const float* __restrict__ x, const float* __restrict__ occ_w,
    const float* __restrict__ occ_b, int* __restrict__ reg_indx,
    float* __restrict__ reg_logit, ushort* __restrict__ xb)
{
    const int wave = threadIdx.x >> 6, lane = threadIdx.x & 63;
    const int row = blockIdx.x * 4 + wave;
    const float* xr = x + (size_t)row * D;
    double acc[R];
#pragma unroll
    for (int r = 0; r < R; ++r) acc[r] = 0.0;
#pragma unroll
    for (int it = 0; it < D / 64; ++it) {
        const int d = it * 64 + lane;
        const float xv = xr[d];
        xb[(size_t)row * D + d] = f2bf(xv);
        const double xd = (double)xv;
        const float* wr = occ_w + d * R;
#pragma unroll
        for (int r = 0; r < R; ++r) acc[r] += xd * (double)wr[r];
    }
#pragma unroll
    for (int r = 0; r < R; ++r) {
        double v = acc[r];
#pragma unroll
        for (int off = 32; off > 0; off >>= 1) v += __shfl_xor(v, off, 64);
        acc[r] = v + (double)occ_b[r];
    }
    double mx = acc[0]; int idx = 0;
#pragma unroll
    for (int r = 1; r < R; ++r) if (acc[r] > mx) { mx = acc[r]; idx = r; }
    double sum = 0.0;
#pragma unroll
    for (int r = 0; r < R; ++r) sum += exp(acc[r] - mx);
    if (lane == 0) { reg_indx[row] = idx; reg_logit[row] = (float)(1.0 / sum); }
}

// ---------------- per-batch counts + loss partial (deterministic) -----------
__global__ __launch_bounds__(256) void loss_kernel(
    const int* __restrict__ reg_indx, const float* __restrict__ reg_logit,
    int* __restrict__ counts, double* __restrict__ loss_b)
{
    const int b = blockIdx.x, t = threadIdx.x;
    __shared__ double ssum[R][257];
    __shared__ int    scnt[R][257];
#pragma unroll
    for (int r = 0; r < R; ++r) { ssum[r][t] = 0.0; scnt[r][t] = 0; }
    __syncthreads();
    for (int s = t; s < S; s += 256) {
        const int r = reg_indx[b * S + s];
        ssum[r][t] += (double)reg_logit[b * S + s];
        scnt[r][t] += 1;
    }
    __syncthreads();
    for (int off = 128; off > 0; off >>= 1) {
        if (t < off) {
#pragma unroll
            for (int r = 0; r < R; ++r) {
                ssum[r][t] += ssum[r][t + off];
                scnt[r][t] += scnt[r][t + off];
            }
        }
        __syncthreads();
    }
    if (t == 0) {
        double lb = 0.0;
#pragma unroll
        for (int r = 0; r < R; ++r) {
            counts[b * R + r] = scnt[r][0];
            const double mean = ssum[r][0] / (double)S;
            lb += mean * mean;
        }
        loss_b[b] = lb;
    }
}

// ---------------- c2 = relu(relu(b1) @ w2 + b2) ------------------------------
__global__ __launch_bounds__(256) void c2_kernel(
    const float* __restrict__ b1, const float* __restrict__ w2,
    const float* __restrict__ b2, float* __restrict__ c2)
{
    __shared__ float c1[D];
    const int t = threadIdx.x;
    c1[t]       = fmaxf(b1[t], 0.f);
    c1[t + 256] = fmaxf(b1[t + 256], 0.f);
    __syncthreads();
    for (int d = t; d < D; d += 256) {
        float acc = b2[d];
        for (int k = 0; k < D; ++k) acc += c1[k] * w2[(size_t)k * D + d];
        c2[d] = fmaxf(acc, 0.f);
    }
}

// ---------------- init regvec[b][r][:] = (count<S) ? c2 : 0 ------------------
__global__ __launch_bounds__(256) void init_regvec_kernel(
    const int* __restrict__ counts, const float* __restrict__ c2,
    float* __restrict__ regvec)
{
    const int idx = blockIdx.x * 256 + threadIdx.x;
    const int d = idx & (D - 1);
    const int br = idx >> 9;
    regvec[idx] = (counts[br] < S) ? c2[d] : 0.f;
}

// ---------------- weight transpose + bf16 convert: wt[n][k] = w[k][n] --------
__global__ __launch_bounds__(256) void wtrans_kernel(
    const float* __restrict__ w, ushort* __restrict__ wt)
{
    __shared__ float tile[32][33];
    const int tx = threadIdx.x & 31, ty = threadIdx.x >> 5;   // ty: 0..7
    const int n0 = blockIdx.x * 32, k0 = blockIdx.y * 32;
#pragma unroll
    for (int q = 0; q < 4; ++q)
        tile[ty * 4 + q][tx] = w[(size_t)(k0 + ty * 4 + q) * D + n0 + tx];
    __syncthreads();
#pragma unroll
    for (int q = 0; q < 4; ++q)
        wt[(size_t)(n0 + ty * 4 + q) * D + k0 + tx] = f2bf(tile[tx][ty * 4 + q]);
}

// ================= MFMA GEMM: 128x128 tile, 4 waves, 16x16x32 bf16 ==========
// LDS tiles are [128 rows][32 k] bf16 with XOR swizzle byte^=((row&7)<<4).
// global_load_lds writes LINEAR LDS; the global source address is
// inverse-swizzled per lane (guideline 21).  ds_read_b128 uses the swizzled
// offset -> 2-way max bank aliasing (free).

struct GemmCtx {
    int row0, col0, wave, lane, wr, wc;
    unsigned dsto[2];
    const ushort *aSrc[2], *bSrc[2];
    unsigned aOff[4], bOff[4];
};

__device__ __forceinline__ void gemm_setup(
    GemmCtx& c, const ushort* Ab, const ushort* Bt)
{
    const int tid = threadIdx.x;
    c.wave = tid >> 6; c.lane = tid & 63;
    c.wr = c.wave >> 1; c.wc = c.wave & 1;
    // bijective XCD swizzle over nwg=1024 (8 XCDs x 128 chunks)
    const int orig = blockIdx.x;
    const int wg = (orig & 7) * 128 + (orig >> 3);
    c.row0 = (wg >> 2) * 128;   // 256 mtiles
    c.col0 = (wg & 3) * 128;    // 4 ntiles
#pragma unroll
    for (int q = 0; q < 2; ++q) {
        const unsigned o = (unsigned)(c.wave * 2 + q) * 1024u + (unsigned)c.lane * 16u;
        c.dsto[q] = (unsigned)(c.wave * 2 + q) * 1024u;
        const unsigned r  = ((o >> 7) << 1) | (((o >> 6) ^ (o >> 8)) & 1u);
        const unsigned kg = ((o >> 4) & 3u) ^ (r & 3u);
        c.aSrc[q] = Ab + (size_t)(c.row0 + r) * D + kg * 8;
        c.bSrc[q] = Bt + (size_t)(c.col0 + r) * D + kg * 8;
    }
#pragma unroll
    for (int i = 0; i < 4; ++i) {
        const unsigned kg = (unsigned)(c.lane >> 4);
        unsigned r = (unsigned)(c.wr * 64 + i * 16 + (c.lane & 15));
        c.aOff[i] = ((r << 6) + (kg << 4)) ^ ((r & 7u) << 4);
        r = (unsigned)(c.wc * 64 + i * 16 + (c.lane & 15));
        c.bOff[i] = ((r << 6) + (kg << 4)) ^ ((r & 7u) << 4);
    }
}

#define GEMM_KLOOP(smA, smB, ctx, acc)                                          \
    for (int kt = 0; kt < D; kt += 32) {                                        \
        __syncthreads();                                                        \
        gload_lds16(ctx.aSrc[0] + kt, smA + ctx.dsto[0]);                       \
        gload_lds16(ctx.aSrc[1] + kt, smA + ctx.dsto[1]);                       \
        gload_lds16(ctx.bSrc[0] + kt, smB + ctx.dsto[0]);                       \
        gload_lds16(ctx.bSrc[1] + kt, smB + ctx.dsto[1]);                       \
        __syncthreads();                                                        \
        short8 a[4], b[4];                                                      \
        _Pragma("unroll")                                                       \
        for (int i = 0; i < 4; ++i) a[i] = *(const short8*)(smA + ctx.aOff[i]); \
        _Pragma("unroll")                                                       \
        for (int j = 0; j < 4; ++j) b[j] = *(const short8*)(smB + ctx.bOff[j]); \
        _Pragma("unroll")                                                       \
        for (int i = 0; i < 4; ++i)                                             \
            _Pragma("unroll")                                                   \
            for (int j = 0; j < 4; ++j)                                         \
                acc[i][j] = __builtin_amdgcn_mfma_f32_16x16x32_bf16(            \
                    a[i], b[j], acc[i][j], 0, 0, 0);                            \
    }

// GEMM1: h1 = relu(xb @ w1t^T + b1), bf16 out
__global__ __launch_bounds__(256, 2) void gemm_mfma1(
    const ushort* __restrict__ Ab, const ushort* __restrict__ Bt,
    const float* __restrict__ bias, ushort* __restrict__ H)
{
    __shared__ ushort As[4096];
    __shared__ ushort Bs[4096];
    GemmCtx c; gemm_setup(c, Ab, Bt);
    char* smA = (char*)As; char* smB = (char*)Bs;
    f32x4 acc[4][4];
#pragma unroll
    for (int i = 0; i < 4; ++i)
#pragma unroll
        for (int j = 0; j < 4; ++j) acc[i][j] = (f32x4)0.f;
    GEMM_KLOOP(smA, smB, c, acc)
    float bb[4];
#pragma unroll
    for (int j = 0; j < 4; ++j) bb[j] = bias[c.col0 + c.wc * 64 + j * 16 + (c.lane & 15)];
#pragma unroll
    for (int i = 0; i < 4; ++i) {
        const int row = c.row0 + c.wr * 64 + i * 16 + ((c.lane >> 4) << 2);
#pragma unroll
        for (int j = 0; j < 4; ++j) {
            const int col = c.col0 + c.wc * 64 + j * 16 + (c.lane & 15);
#pragma unroll
            for (int ii = 0; ii < 4; ++ii) {
                const float v = fmaxf(acc[i][j][ii] + bb[j], 0.f);
                H[(size_t)(row + ii) * D + col] = f2bf(v);
            }
        }
    }
}

// GEMM2: v = relu(h1 @ w2t^T + b2); segmented max by reg_indx into regvec
__global__ __launch_bounds__(256, 2) void gemm_mfma2(
    const ushort* __restrict__ Ab, const ushort* __restrict__ Bt,
    const float* __restrict__ bias, const int* __restrict__ reg_indx,
    float* __restrict__ regvec)
{
    __shared__ ushort As[4096];
    __shared__ ushort Bs[4096];
    __shared__ unsigned redmax[R * 128];
    __shared__ int rowreg[128];
    GemmCtx c; gemm_setup(c, Ab, Bt);
    char* smA = (char*)As; char* smB = (char*)Bs;
    const int tid = threadIdx.x;
    if (tid < 128) rowreg[tid] = reg_indx[c.row0 + tid];
#pragma unroll
    for (int q = 0; q < 8; ++q) redmax[tid + q * 256] = 0u;
    f32x4 acc[4][4];
#pragma unroll
    for (int i = 0; i < 4; ++i)
#pragma unroll
        for (int j = 0; j < 4; ++j) acc[i][j] = (f32x4)0.f;
    GEMM_KLOOP(smA, smB, c, acc)   // first barrier inside makes init visible
    float bb[4];
#pragma unroll
    for (int j = 0; j < 4; ++j) bb[j] = bias[c.col0 + c.wc * 64 + j * 16 + (c.lane & 15)];
#pragma unroll
    for (int i = 0; i < 4; ++i) {
        const int lrow = c.wr * 64 + i * 16 + ((c.lane >> 4) << 2);
#pragma unroll
        for (int j = 0; j < 4; ++j) {
            const int lcol = c.wc * 64 + j * 16 + (c.lane & 15);
#pragma unroll
            for (int ii = 0; ii < 4; ++ii) {
                const float v = fmaxf(acc[i][j][ii] + bb[j], 0.f);
                atomicMax(&redmax[rowreg[lrow + ii] * 128 + lcol], __float_as_uint(v));
            }
        }
    }
    __syncthreads();
    const int b = c.row0 >> 12;
#pragma unroll
    for (int q = 0; q < 8; ++q) {
        const int idx = tid + q * 256;
        const int r = idx >> 7, col = idx & 127;
        atomicMax((unsigned*)&regvec[(((size_t)b * R + r) << 9) + c.col0 + col],
                  redmax[idx]);
    }
}

// ---------------- output assembly: [x | regvec[reg_indx] | g] ----------------
__global__ __launch_bounds__(128) void out_kernel(
    const float* __restrict__ x, const float* __restrict__ g,
    const float* __restrict__ regvec, const int* __restrict__ reg_indx,
    float* __restrict__ out)
{
    const int row = blockIdx.x;
    const int t = threadIdx.x;
    const int b = row >> 12;
    const int r = reg_indx[row];
    const float4* xr = (const float4*)(x + (size_t)row * D);
    const float4* rv = (const float4*)(regvec + ((size_t)b * R + r) * D);
    const float4* gr = (const float4*)(g + (size_t)b * D);
    float4* o = (float4*)(out + (size_t)row * 3 * D);
    o[t]       = xr[t];
    o[128 + t] = rv[t];
    o[256 + t] = gr[t];
}

__global__ void loss_final_kernel(const double* __restrict__ loss_b,
                                  float* __restrict__ out_loss)
{
    if (threadIdx.x == 0) {
        double s = 0.0;
        for (int b = 0; b < B; ++b) s += loss_b[b];
        *out_loss = (float)(s / (double)B);
    }
}

extern "C" void kernel_launch(void* const* d_in, const int* in_sizes, int n_in,
                              void* d_out, int out_size, void* d_ws, size_t ws_size,
                              hipStream_t stream)
{
    (void)in_sizes; (void)n_in; (void)out_size;
    const float* x     = (const float*)d_in[0];
    const float* g_vec = (const float*)d_in[1];
    const float* occ_w = (const float*)d_in[2];
    const float* occ_b = (const float*)d_in[3];
    const float* w1    = (const float*)d_in[4];
    const float* b1    = (const float*)d_in[5];
    const float* w2    = (const float*)d_in[6];
    const float* b2    = (const float*)d_in[7];
    float* out = (float*)d_out;

    char* ws = (char*)d_ws;
    size_t off = 0;
    auto alloc = [&](size_t bytes) {
        char* p = ws + off; off = (off + bytes + 255) & ~(size_t)255; return p;
    };
    double* loss_b    = (double*)alloc(64);
    int*    reg_indx  = (int*)alloc((size_t)M * 4);
    float*  reg_logit = (float*)alloc((size_t)M * 4);
    int*    counts    = (int*)alloc(B * R * 4);
    float*  c2        = (float*)alloc(D * 4);
    float*  regvec    = (float*)alloc((size_t)B * R * D * 4);

    const size_t xbB = (size_t)M * D * 2, wB = (size_t)D * D * 2;
    ushort *xb, *h1, *w1t, *w2t;
    if (ws_size >= off + 2 * xbB + 2 * wB + 1024) {
        xb  = (ushort*)alloc(xbB);
        h1  = (ushort*)alloc(xbB);
        w1t = (ushort*)alloc(wB);
        w2t = (ushort*)alloc(wB);
    } else {                         // carve from d_out; fully rewritten later
        char* o = (char*)d_out;
        xb  = (ushort*)o;
        h1  = (ushort*)(o + xbB);
        w1t = (ushort*)(o + 2 * xbB);
        w2t = (ushort*)(o + 2 * xbB + wB);
    }

    hipLaunchKernelGGL(occ_kernel, dim3(M / 4), dim3(256), 0, stream,
                       x, occ_w, occ_b, reg_indx, reg_logit, xb);
    hipLaunchKernelGGL(loss_kernel, dim3(B), dim3(256), 0, stream,
                       reg_indx, reg_logit, counts, loss_b);
    hipLaunchKernelGGL(c2_kernel, dim3(1), dim3(256), 0, stream,
                       b1, w2, b2, c2);
    hipLaunchKernelGGL(init_regvec_kernel, dim3(B * R * D / 256), dim3(256), 0, stream,
                       counts, c2, regvec);
    hipLaunchKernelGGL(wtrans_kernel, dim3(16, 16), dim3(256), 0, stream, w1, w1t);
    hipLaunchKernelGGL(wtrans_kernel, dim3(16, 16), dim3(256), 0, stream, w2, w2t);
    hipLaunchKernelGGL(gemm_mfma1, dim3((M / 128) * (D / 128)), dim3(256), 0, stream,
                       xb, w1t, b1, h1);
    hipLaunchKernelGGL(gemm_mfma2, dim3((M / 128) * (D / 128)), dim3(256), 0, stream,
                       h1, w2t, b2, reg_indx, regvec);
    hipLaunchKernelGGL(out_kernel, dim3(M), dim3(128), 0, stream,
                       x, g_vec, regvec, reg_indx, out);
    hipLaunchKernelGGL(loss_final_kernel, dim3(1), dim3(64), 0, stream,
                       loss_b, out + OUT_ELEMS);
}

// Round 3
// 199.533 us; speedup vs baseline: 3.1699x; 1.2004x over previous
//
#include <hip/hip_runtime.h>
#include <cstdint>
#include <cstddef>

constexpr int B = 8, S = 4096, D = 512, R = 16;
constexpr int M = B * S;                         // 32768 rows
constexpr long long OUT_ELEMS = (long long)M * 3 * D;  // 50331648

typedef short short8 __attribute__((ext_vector_type(8)));
typedef float f32x4 __attribute__((ext_vector_type(4)));

__device__ __forceinline__ ushort f2bf(float f) {
    union { float f; unsigned u; } v; v.f = f;
    return (ushort)((v.u + 0x7fffu + ((v.u >> 16) & 1u)) >> 16);
}

__device__ __forceinline__ void gload_lds16(const void* g, void* l) {
    __builtin_amdgcn_global_load_lds(
        (const __attribute__((address_space(1))) void*)g,
        (__attribute__((address_space(3))) void*)l, 16, 0, 0);
}

// ---------------- occ: fp64 dot -> LDS transpose reduce -> argmax + fp32 exp
// Each lane ends up owning logit r = lane&15; 2 rows per wave, 8 rows/block.
__global__ __launch_bounds__(256) void occ_kernel(
    const float* __restrict__ x, const float* __restrict__ occ_w,
    const float* __restrict__ occ_b, int* __restrict__ reg_indx,
    float* __restrict__ reg_logit, ushort* __restrict__ xb)
{
    __shared__ double red[4][16][65];
    const int wave = threadIdx.x >> 6, lane = threadIdx.x & 63;
    const int q = lane >> 4, sidx = lane & 15;
    const double bias = (double)occ_b[sidx];
    for (int rr = 0; rr < 2; ++rr) {
        const int row = blockIdx.x * 8 + wave * 2 + rr;
        const float* xr = x + (size_t)row * D;
        double acc[R];
#pragma unroll
        for (int r = 0; r < R; ++r) acc[r] = 0.0;
#pragma unroll
        for (int it = 0; it < D / 64; ++it) {
            const int d = it * 64 + lane;
            const float xv = xr[d];
            xb[(size_t)row * D + d] = f2bf(xv);
            const double xd = (double)xv;
            const float4 wa = *(const float4*)&occ_w[d * 16];
            const float4 wb = *(const float4*)&occ_w[d * 16 + 4];
            const float4 wc = *(const float4*)&occ_w[d * 16 + 8];
            const float4 wd = *(const float4*)&occ_w[d * 16 + 12];
            acc[0]  += xd * (double)wa.x; acc[1]  += xd * (double)wa.y;
            acc[2]  += xd * (double)wa.z; acc[3]  += xd * (double)wa.w;
            acc[4]  += xd * (double)wb.x; acc[5]  += xd * (double)wb.y;
            acc[6]  += xd * (double)wb.z; acc[7]  += xd * (double)wb.w;
            acc[8]  += xd * (double)wc.x; acc[9]  += xd * (double)wc.y;
            acc[10] += xd * (double)wc.z; acc[11] += xd * (double)wc.w;
            acc[12] += xd * (double)wd.x; acc[13] += xd * (double)wd.y;
            acc[14] += xd * (double)wd.z; acc[15] += xd * (double)wd.w;
        }
#pragma unroll
        for (int r = 0; r < R; ++r) red[wave][r][q * 16 + sidx] = acc[r];
        __syncthreads();
        double s = 0.0;
#pragma unroll
        for (int j = 0; j < 16; ++j) s += red[wave][sidx][q * 16 + j];
        __syncthreads();   // frees red[] for next rr
        s += __shfl_xor(s, 16, 64);
        s += __shfl_xor(s, 32, 64);
        s += bias;         // lane's logit for r = sidx (full fp64 sum)
        double mv = s; int mi = sidx;
#pragma unroll
        for (int off = 1; off < 16; off <<= 1) {
            const double ov = __shfl_xor(mv, off, 64);
            const int    oi = __shfl_xor(mi, off, 64);
            if (ov > mv || (ov == mv && oi < mi)) { mv = ov; mi = oi; }
        }
        float ef = expf((float)(s - mv));
#pragma unroll
        for (int off = 1; off < 16; off <<= 1) ef += __shfl_xor(ef, off, 64);
        if (lane == 0) { reg_indx[row] = mi; reg_logit[row] = 1.0f / ef; }
    }
}

// ---------------- loss partials: 64 blocks = (batch, chunk-of-512-rows) ----
__global__ __launch_bounds__(256) void loss_part_kernel(
    const int* __restrict__ reg_indx, const float* __restrict__ reg_logit,
    int* __restrict__ pcnt, double* __restrict__ psum)
{
    const int b = blockIdx.x >> 3, c = blockIdx.x & 7;
    const int t = threadIdx.x;
    __shared__ double ssum[R][257];
    __shared__ int    scnt[R][257];
#pragma unroll
    for (int r = 0; r < R; ++r) { ssum[r][t] = 0.0; scnt[r][t] = 0; }
    __syncthreads();
    const int base = b * S + c * 512;
    for (int s = t; s < 512; s += 256) {
        const int r = reg_indx[base + s];
        ssum[r][t] += (double)reg_logit[base + s];
        scnt[r][t] += 1;
    }
    __syncthreads();
    for (int off = 128; off > 0; off >>= 1) {
        if (t < off) {
#pragma unroll
            for (int r = 0; r < R; ++r) {
                ssum[r][t] += ssum[r][t + off];
                scnt[r][t] += scnt[r][t + off];
            }
        }
        __syncthreads();
    }
    if (t < R) {
        psum[blockIdx.x * R + t] = ssum[t][0];
        pcnt[blockIdx.x * R + t] = scnt[t][0];
    }
}

// ---------------- loss final: combine partials, emit counts + scalar loss ---
__global__ void loss_final_kernel(const int* __restrict__ pcnt,
                                  const double* __restrict__ psum,
                                  int* __restrict__ counts,
                                  float* __restrict__ out_loss)
{
    __shared__ double m2[128];
    const int t = threadIdx.x;            // 128 threads = (b,r)
    const int b = t >> 4, r = t & 15;
    int cnt = 0; double s = 0.0;
#pragma unroll
    for (int c = 0; c < 8; ++c) {
        cnt += pcnt[(b * 8 + c) * R + r];
        s   += psum[(b * 8 + c) * R + r];
    }
    counts[b * R + r] = cnt;
    const double mean = s / (double)S;
    m2[t] = mean * mean;
    __syncthreads();
    if (t == 0) {
        double tot = 0.0;
        for (int i = 0; i < 128; ++i) tot += m2[i];
        *out_loss = (float)(tot / (double)B);
    }
}

// ---------------- fused c2 compute + regvec init -----------------------------
// c2 = relu(relu(b1) @ w2 + b2); regvec[b][r][:] = (count<S) ? c2 : 0
__global__ __launch_bounds__(256) void init_regvec_c2_kernel(
    const float* __restrict__ b1, const float* __restrict__ w2,
    const float* __restrict__ b2, const int* __restrict__ counts,
    float* __restrict__ regvec)
{
    __shared__ float c1[D];
    const int t = threadIdx.x;
    const int d = blockIdx.x * 256 + t;
    c1[t]       = fmaxf(b1[t], 0.f);
    c1[t + 256] = fmaxf(b1[t + 256], 0.f);
    __syncthreads();
    float acc = b2[d];
    for (int k = 0; k < D; ++k) acc += c1[k] * w2[(size_t)k * D + d];
    const float c2d = fmaxf(acc, 0.f);
    for (int br = 0; br < B * R; ++br)
        regvec[(size_t)br * D + d] = (counts[br] < S) ? c2d : 0.f;
}

// ---------------- weight transpose + bf16: both weights, one launch ---------
__global__ __launch_bounds__(256) void wtrans_kernel(
    const float* __restrict__ w1, const float* __restrict__ w2,
    ushort* __restrict__ w1t, ushort* __restrict__ w2t)
{
    __shared__ float tile[32][33];
    const float* w = blockIdx.z ? w2 : w1;
    ushort* wt = blockIdx.z ? w2t : w1t;
    const int tx = threadIdx.x & 31, ty = threadIdx.x >> 5;   // ty: 0..7
    const int n0 = blockIdx.x * 32, k0 = blockIdx.y * 32;
#pragma unroll
    for (int qq = 0; qq < 4; ++qq)
        tile[ty * 4 + qq][tx] = w[(size_t)(k0 + ty * 4 + qq) * D + n0 + tx];
    __syncthreads();
#pragma unroll
    for (int qq = 0; qq < 4; ++qq)
        wt[(size_t)(n0 + ty * 4 + qq) * D + k0 + tx] = f2bf(tile[tx][ty * 4 + qq]);
}

// ================= MFMA GEMM: 128x128 tile, 4 waves, 16x16x32 bf16 ==========
// Double-buffered LDS (2x8KB per operand).  Prefetch of K-tile t+1 is issued
// BEFORE the ds_read+MFMA of tile t; one barrier per iteration (T3-minimum).
// XOR swizzle byte^=((row&7)<<4) applied on the inverse-swizzled global source
// (global_load_lds writes linear LDS) and on the ds_read offsets.

struct GemmCtx {
    int row0, col0, wave, lane, wr, wc;
    unsigned dsto[2];
    const ushort *aSrc[2], *bSrc[2];
    unsigned aOff[4], bOff[4];
};

__device__ __forceinline__ void gemm_setup(
    GemmCtx& c, const ushort* Ab, const ushort* Bt)
{
    const int tid = threadIdx.x;
    c.wave = tid >> 6; c.lane = tid & 63;
    c.wr = c.wave >> 1; c.wc = c.wave & 1;
    // bijective XCD swizzle over nwg=1024 (8 XCDs x 128 chunks)
    const int orig = blockIdx.x;
    const int wg = (orig & 7) * 128 + (orig >> 3);
    c.row0 = (wg >> 2) * 128;   // 256 mtiles
    c.col0 = (wg & 3) * 128;    // 4 ntiles
#pragma unroll
    for (int q = 0; q < 2; ++q) {
        const unsigned o = (unsigned)(c.wave * 2 + q) * 1024u + (unsigned)c.lane * 16u;
        c.dsto[q] = (unsigned)(c.wave * 2 + q) * 1024u;
        const unsigned r  = ((o >> 7) << 1) | (((o >> 6) ^ (o >> 8)) & 1u);
        const unsigned kg = ((o >> 4) & 3u) ^ (r & 3u);
        c.aSrc[q] = Ab + (size_t)(c.row0 + r) * D + kg * 8;
        c.bSrc[q] = Bt + (size_t)(c.col0 + r) * D + kg * 8;
    }
#pragma unroll
    for (int i = 0; i < 4; ++i) {
        const unsigned kg = (unsigned)(c.lane >> 4);
        unsigned r = (unsigned)(c.wr * 64 + i * 16 + (c.lane & 15));
        c.aOff[i] = ((r << 6) + (kg << 4)) ^ ((r & 7u) << 4);
        r = (unsigned)(c.wc * 64 + i * 16 + (c.lane & 15));
        c.bOff[i] = ((r << 6) + (kg << 4)) ^ ((r & 7u) << 4);
    }
}

#define STAGE4(ctx, smA, smB, bufofs, kt)                                 \
    gload_lds16(ctx.aSrc[0] + (kt), smA + (bufofs) + ctx.dsto[0]);        \
    gload_lds16(ctx.aSrc[1] + (kt), smA + (bufofs) + ctx.dsto[1]);        \
    gload_lds16(ctx.bSrc[0] + (kt), smB + (bufofs) + ctx.dsto[0]);        \
    gload_lds16(ctx.bSrc[1] + (kt), smB + (bufofs) + ctx.dsto[1]);

#define GEMM_KLOOP(smA, smB, ctx, acc)                                         \
    STAGE4(ctx, smA, smB, 0, 0)                                                \
    __syncthreads();                                                           \
    _Pragma("unroll")                                                          \
    for (int t = 0; t < 16; ++t) {                                             \
        const int co = (t & 1) * 8192;                                         \
        if (t < 15) { STAGE4(ctx, smA, smB, co ^ 8192, (t + 1) * 32) }         \
        short8 a[4], b[4];                                                     \
        _Pragma("unroll")                                                      \
        for (int i = 0; i < 4; ++i)                                            \
            a[i] = *(const short8*)(smA + co + ctx.aOff[i]);                   \
        _Pragma("unroll")                                                      \
        for (int j = 0; j < 4; ++j)                                            \
            b[j] = *(const short8*)(smB + co + ctx.bOff[j]);                   \
        _Pragma("unroll")                                                      \
        for (int i = 0; i < 4; ++i)                                            \
            _Pragma("unroll")                                                  \
            for (int j = 0; j < 4; ++j)                                        \
                acc[i][j] = __builtin_amdgcn_mfma_f32_16x16x32_bf16(           \
                    a[i], b[j], acc[i][j], 0, 0, 0);                           \
        __syncthreads();                                                       \
    }

// GEMM1: h1 = relu(xb @ w1t^T + b1), bf16 out
__global__ __launch_bounds__(256, 2) void gemm_mfma1(
    const ushort* __restrict__ Ab, const ushort* __restrict__ Bt,
    const float* __restrict__ bias, ushort* __restrict__ H)
{
    __shared__ ushort As[8192];
    __shared__ ushort Bs[8192];
    GemmCtx c; gemm_setup(c, Ab, Bt);
    char* smA = (char*)As; char* smB = (char*)Bs;
    f32x4 acc[4][4];
#pragma unroll
    for (int i = 0; i < 4; ++i)
#pragma unroll
        for (int j = 0; j < 4; ++j) acc[i][j] = (f32x4)0.f;
    GEMM_KLOOP(smA, smB, c, acc)
    float bb[4];
#pragma unroll
    for (int j = 0; j < 4; ++j) bb[j] = bias[c.col0 + c.wc * 64 + j * 16 + (c.lane & 15)];
#pragma unroll
    for (int i = 0; i < 4; ++i) {
        const int row = c.row0 + c.wr * 64 + i * 16 + ((c.lane >> 4) << 2);
#pragma unroll
        for (int j = 0; j < 4; ++j) {
            const int col = c.col0 + c.wc * 64 + j * 16 + (c.lane & 15);
#pragma unroll
            for (int ii = 0; ii < 4; ++ii) {
                const float v = fmaxf(acc[i][j][ii] + bb[j], 0.f);
                H[(size_t)(row + ii) * D + col] = f2bf(v);
            }
        }
    }
}

// GEMM2: v = relu(h1 @ w2t^T + b2); segmented max by reg_indx into regvec
__global__ __launch_bounds__(256, 2) void gemm_mfma2(
    const ushort* __restrict__ Ab, const ushort* __restrict__ Bt,
    const float* __restrict__ bias, const int* __restrict__ reg_indx,
    float* __restrict__ regvec)
{
    __shared__ ushort As[8192];
    __shared__ ushort Bs[8192];
    __shared__ unsigned redmax[R * 128];
    __shared__ int rowreg[128];
    GemmCtx c; gemm_setup(c, Ab, Bt);
    char* smA = (char*)As; char* smB = (char*)Bs;
    const int tid = threadIdx.x;
    if (tid < 128) rowreg[tid] = reg_indx[c.row0 + tid];
#pragma unroll
    for (int q = 0; q < 8; ++q) redmax[tid + q * 256] = 0u;
    f32x4 acc[4][4];
#pragma unroll
    for (int i = 0; i < 4; ++i)
#pragma unroll
        for (int j = 0; j < 4; ++j) acc[i][j] = (f32x4)0.f;
    GEMM_KLOOP(smA, smB, c, acc)   // barriers inside make the init visible
    float bb[4];
#pragma unroll
    for (int j = 0; j < 4; ++j) bb[j] = bias[c.col0 + c.wc * 64 + j * 16 + (c.lane & 15)];
#pragma unroll
    for (int i = 0; i < 4; ++i) {
        const int lrow = c.wr * 64 + i * 16 + ((c.lane >> 4) << 2);
#pragma unroll
        for (int j = 0; j < 4; ++j) {
            const int lcol = c.wc * 64 + j * 16 + (c.lane & 15);
#pragma unroll
            for (int ii = 0; ii < 4; ++ii) {
                const float v = fmaxf(acc[i][j][ii] + bb[j], 0.f);
                atomicMax(&redmax[rowreg[lrow + ii] * 128 + lcol], __float_as_uint(v));
            }
        }
    }
    __syncthreads();
    const int b = c.row0 >> 12;
#pragma unroll
    for (int q = 0; q < 8; ++q) {
        const int idx = tid + q * 256;
        const int r = idx >> 7, col = idx & 127;
        atomicMax((unsigned*)&regvec[(((size_t)b * R + r) << 9) + c.col0 + col],
                  redmax[idx]);
    }
}

// ---------------- output assembly: [x | regvec[reg_indx] | g] ----------------
__global__ __launch_bounds__(256) void out_kernel(
    const float* __restrict__ x, const float* __restrict__ g,
    const float* __restrict__ regvec, const int* __restrict__ reg_indx,
    float* __restrict__ out)
{
    const int row = blockIdx.x * 2 + (threadIdx.x >> 7);
    const int t = threadIdx.x & 127;
    const int b = row >> 12;
    const int r = reg_indx[row];
    const float4* xr = (const float4*)(x + (size_t)row * D);
    const float4* rv = (const float4*)(regvec + ((size_t)b * R + r) * D);
    const float4* gr = (const float4*)(g + (size_t)b * D);
    float4* o = (float4*)(out + (size_t)row * 3 * D);
    o[t]       = xr[t];
    o[128 + t] = rv[t];
    o[256 + t] = gr[t];
}

extern "C" void kernel_launch(void* const* d_in, const int* in_sizes, int n_in,
                              void* d_out, int out_size, void* d_ws, size_t ws_size,
                              hipStream_t stream)
{
    (void)in_sizes; (void)n_in; (void)out_size;
    const float* x     = (const float*)d_in[0];
    const float* g_vec = (const float*)d_in[1];
    const float* occ_w = (const float*)d_in[2];
    const float* occ_b = (const float*)d_in[3];
    const float* w1    = (const float*)d_in[4];
    const float* b1    = (const float*)d_in[5];
    const float* w2    = (const float*)d_in[6];
    const float* b2    = (const float*)d_in[7];
    float* out = (float*)d_out;

    char* ws = (char*)d_ws;
    size_t off = 0;
    auto alloc = [&](size_t bytes) {
        char* p = ws + off; off = (off + bytes + 255) & ~(size_t)255; return p;
    };
    int*    reg_indx  = (int*)alloc((size_t)M * 4);
    float*  reg_logit = (float*)alloc((size_t)M * 4);
    int*    pcnt      = (int*)alloc(64 * R * 4);
    double* psum      = (double*)alloc(64 * R * 8);
    int*    counts    = (int*)alloc(B * R * 4);
    float*  regvec    = (float*)alloc((size_t)B * R * D * 4);

    const size_t xbB = (size_t)M * D * 2, wB = (size_t)D * D * 2;
    ushort *xb, *h1, *w1t, *w2t;
    if (ws_size >= off + 2 * xbB + 2 * wB + 1024) {
        xb  = (ushort*)alloc(xbB);
        h1  = (ushort*)alloc(xbB);
        w1t = (ushort*)alloc(wB);
        w2t = (ushort*)alloc(wB);
    } else {                         // carve from d_out; fully rewritten later
        char* o = (char*)d_out;
        xb  = (ushort*)o;
        h1  = (ushort*)(o + xbB);
        w1t = (ushort*)(o + 2 * xbB);
        w2t = (ushort*)(o + 2 * xbB + wB);
    }

    hipLaunchKernelGGL(occ_kernel, dim3(M / 8), dim3(256), 0, stream,
                       x, occ_w, occ_b, reg_indx, reg_logit, xb);
    hipLaunchKernelGGL(wtrans_kernel, dim3(16, 16, 2), dim3(256), 0, stream,
                       w1, w2, w1t, w2t);
    hipLaunchKernelGGL(loss_part_kernel, dim3(64), dim3(256), 0, stream,
                       reg_indx, reg_logit, pcnt, psum);
    hipLaunchKernelGGL(loss_final_kernel, dim3(1), dim3(128), 0, stream,
                       pcnt, psum, counts, out + OUT_ELEMS);
    hipLaunchKernelGGL(init_regvec_c2_kernel, dim3(2), dim3(256), 0, stream,
                       b1, w2, b2, counts, regvec);
    hipLaunchKernelGGL(gemm_mfma1, dim3((M / 128) * (D / 128)), dim3(256), 0, stream,
                       xb, w1t, b1, h1);
    hipLaunchKernelGGL(gemm_mfma2, dim3((M / 128) * (D / 128)), dim3(256), 0, stream,
                       h1, w2t, b2, reg_indx, regvec);
    hipLaunchKernelGGL(out_kernel, dim3(M / 2), dim3(256), 0, stream,
                       x, g_vec, regvec, reg_indx, out);
}